// Round 8
// baseline (579.298 us; speedup 1.0000x reference)
//
#include <hip/hip_runtime.h>

// Segment-average pooling, sort+gather, ZERO barriers/atomics in hot kernel.
//   input  [B=8, C=128, N=65536] fp32, labels [B, N] int32 in [0, 1024)
//   out    [B, S=1024, C=128] fp32 segment means
//
// R8: R7 counters showed the barrier-phased LDS-scatter aggr ran HBM at 41%
// duty (2.6 TB/s, VALU 10%, occupancy 84% — nothing saturated): the
// scatter/reduce/barrier phases leave memory idle. New structure:
//   sort_kernel: per-tile counting sort -> ord[tilebase+sortedpos] = px (u16)
//                (pos inverted in LDS; pos never hits global)
//   aggr_kernel: thread s walks its contiguous ord run per tile and GATHERS
//                values from global. No LDS buf, no __syncthreads, no
//                atomics -> waves free-run, loads continuously in flight.
//                Per-tile window (2x16KB planes + 8KB ord) is L2-resident;
//                every 64B line fully consumed -> HBM traffic ~262 MB.

#define BB 8
#define CC 128
#define NPIX 65536      // 256*256
#define SS 1024
#define TILE 4096
#define NTILES (NPIX / TILE)   // 16
#define THREADS 1024

#define ORD_ELEMS (BB * NPIX)           // u16 pixel-in-tile, sorted by segment
#define OFF_ELEMS (BB * NTILES * SS)    // u16 exclusive offsets per tile

// ---------------- Kernel A: per-tile counting sort -> ord + tileoff --------
__global__ __launch_bounds__(THREADS, 1) void sort_kernel(
    const int* __restrict__ seg, unsigned short* __restrict__ ord,
    unsigned short* __restrict__ tileoff) {
  __shared__ unsigned int hist[SS];
  __shared__ unsigned int wsum[16];
  __shared__ unsigned short obuf[TILE];   // inverted permutation staging
  const int b   = blockIdx.x / NTILES;
  const int t   = blockIdx.x % NTILES;
  const int tid = threadIdx.x;

  hist[tid] = 0u;   // THREADS == SS
  __syncthreads();

  const int base = b * NPIX + t * TILE;
  const int4 lab = reinterpret_cast<const int4*>(seg + base)[tid];
  const unsigned int r0 = atomicAdd(&hist[lab.x], 1u);
  const unsigned int r1 = atomicAdd(&hist[lab.y], 1u);
  const unsigned int r2 = atomicAdd(&hist[lab.z], 1u);
  const unsigned int r3 = atomicAdd(&hist[lab.w], 1u);
  __syncthreads();

  const unsigned int cnt = hist[tid];
  // inclusive wave-scan (64 lanes, shuffle, no barriers)
  unsigned int v = cnt;
  #pragma unroll
  for (int off = 1; off < 64; off <<= 1) {
    const unsigned int u = __shfl_up(v, off);
    if ((tid & 63) >= off) v += u;
  }
  const int w = tid >> 6;
  if ((tid & 63) == 63) wsum[w] = v;
  __syncthreads();
  if (tid < 16) {   // scan the 16 wave totals
    unsigned int x = wsum[tid];
    #pragma unroll
    for (int off = 1; off < 16; off <<= 1) {
      const unsigned int u = __shfl_up(x, off);
      if (tid >= off) x += u;
    }
    wsum[tid] = x;
  }
  __syncthreads();
  const unsigned int woff = (w == 0) ? 0u : wsum[w - 1];
  const unsigned int excl = woff + v - cnt;   // exclusive offset of segment tid
  tileoff[(b * NTILES + t) * SS + tid] = (unsigned short)excl;
  hist[tid] = excl;
  __syncthreads();

  // invert: obuf[sorted position] = pixel index within tile
  const int px = tid << 2;
  obuf[hist[lab.x] + r0] = (unsigned short)(px + 0);
  obuf[hist[lab.y] + r1] = (unsigned short)(px + 1);
  obuf[hist[lab.z] + r2] = (unsigned short)(px + 2);
  obuf[hist[lab.w] + r3] = (unsigned short)(px + 3);
  __syncthreads();

  // coalesced dump: 4 u16 = 8B per thread
  reinterpret_cast<ushort4*>(ord + base)[tid] =
      reinterpret_cast<const ushort4*>(obuf)[tid];
}

// ---------------- Kernel B: free-running gather-reduce ---------------------
// 512 blocks = (image b, channel pair c0); 2 blocks/CU; thread == segment.
__global__ __launch_bounds__(THREADS, 8) void aggr_kernel(
    const float* __restrict__ inp, const unsigned short* __restrict__ ord,
    const unsigned short* __restrict__ tileoff, float* __restrict__ out) {
  const int b   = blockIdx.x >> 6;          // / (CC/2)
  const int c0  = (blockIdx.x & 63) << 1;   // channel pair base
  const int s   = threadIdx.x;              // segment id

  const float* __restrict__ pl0 = inp + ((size_t)b * CC + c0) * NPIX;
  const float* __restrict__ pl1 = pl0 + NPIX;
  const unsigned short* __restrict__ obase = ord + b * NPIX;
  const unsigned short* __restrict__ tob = tileoff + b * NTILES * SS;

  float a0 = 0.f, a1 = 0.f;
  int cnt = 0;

  #pragma unroll 2
  for (int t = 0; t < NTILES; ++t) {
    const int tb = t * TILE;
    const unsigned short* __restrict__ to = tob + t * SS;
    const int beg = to[s];
    const int end = (s == SS - 1) ? TILE : (int)to[s + 1];
    cnt += end - beg;
    const unsigned short* __restrict__ o = obase + tb;

    int j = beg;
    for (; j + 2 <= end; j += 2) {   // 2-wide: 2 ord + 4 value gathers in flight
      const int p0 = o[j];
      const int p1 = o[j + 1];
      const float x0 = pl0[tb + p0];
      const float y0 = pl1[tb + p0];
      const float x1 = pl0[tb + p1];
      const float y1 = pl1[tb + p1];
      a0 += x0 + x1;
      a1 += y0 + y1;
    }
    if (j < end) {
      const int p = o[j];
      a0 += pl0[tb + p];
      a1 += pl1[tb + p];
    }
  }

  const float inv = 1.0f / (float)max(cnt, 1);
  reinterpret_cast<float2*>(out + ((size_t)(b * SS + s)) * CC + c0)[0] =
      make_float2(a0 * inv, a1 * inv);
}

// ---------------- Fallback (R2): LDS-atomic version, needs no ws -----------
__global__ __launch_bounds__(THREADS, 1) void seg_avg_kernel(
    const float* __restrict__ inp, const int* __restrict__ seg,
    float* __restrict__ out) {
  __shared__ float acc[SS * 5];
  const int b   = blockIdx.x >> 5;
  const int c0  = (blockIdx.x & 31) << 2;
  const int tid = threadIdx.x;
  for (int i = tid; i < SS * 5; i += THREADS) acc[i] = 0.0f;
  __syncthreads();
  const float4* __restrict__ p0 =
      reinterpret_cast<const float4*>(inp + ((size_t)b * CC + c0) * NPIX);
  const int4* __restrict__ lab = reinterpret_cast<const int4*>(seg + (size_t)b * NPIX);
  const int Q = NPIX / 4;
  int* iacc = reinterpret_cast<int*>(acc);
  for (int i = 0; i < NPIX / (4 * THREADS); ++i) {
    const int p = i * THREADS + tid;
    const int4 s4 = lab[p];
    const float4 v0 = p0[p], v1 = p0[p + Q], v2 = p0[p + 2 * Q], v3 = p0[p + 3 * Q];
    const int a0 = s4.x * 5, a1 = s4.y * 5, a2 = s4.z * 5, a3 = s4.w * 5;
    unsafeAtomicAdd(&acc[a0 + 0], v0.x); unsafeAtomicAdd(&acc[a0 + 1], v1.x);
    unsafeAtomicAdd(&acc[a0 + 2], v2.x); unsafeAtomicAdd(&acc[a0 + 3], v3.x);
    atomicAdd(&iacc[a0 + 4], 1);
    unsafeAtomicAdd(&acc[a1 + 0], v0.y); unsafeAtomicAdd(&acc[a1 + 1], v1.y);
    unsafeAtomicAdd(&acc[a1 + 2], v2.y); unsafeAtomicAdd(&acc[a1 + 3], v3.y);
    atomicAdd(&iacc[a1 + 4], 1);
    unsafeAtomicAdd(&acc[a2 + 0], v0.z); unsafeAtomicAdd(&acc[a2 + 1], v1.z);
    unsafeAtomicAdd(&acc[a2 + 2], v2.z); unsafeAtomicAdd(&acc[a2 + 3], v3.z);
    atomicAdd(&iacc[a2 + 4], 1);
    unsafeAtomicAdd(&acc[a3 + 0], v0.w); unsafeAtomicAdd(&acc[a3 + 1], v1.w);
    unsafeAtomicAdd(&acc[a3 + 2], v2.w); unsafeAtomicAdd(&acc[a3 + 3], v3.w);
    atomicAdd(&iacc[a3 + 4], 1);
  }
  __syncthreads();
  for (int i = tid; i < SS * 4; i += THREADS) {
    const int s = i >> 2, c = i & 3;
    const float cntf = (float)iacc[s * 5 + 4];
    out[((size_t)(b * SS + s)) * CC + c0 + c] = acc[s * 5 + c] / fmaxf(cntf, 1.0f);
  }
}

extern "C" void kernel_launch(void* const* d_in, const int* in_sizes, int n_in,
                              void* d_out, int out_size, void* d_ws, size_t ws_size,
                              hipStream_t stream) {
  const float* inp = (const float*)d_in[0];
  const int*   seg = (const int*)d_in[1];
  float*       out = (float*)d_out;

  const size_t need = (size_t)ORD_ELEMS * 2 + (size_t)OFF_ELEMS * 2;  // 1.25 MiB
  if (ws_size >= need) {
    unsigned short* ord  = (unsigned short*)d_ws;
    unsigned short* toff = ord + ORD_ELEMS;
    sort_kernel<<<BB * NTILES, THREADS, 0, stream>>>(seg, ord, toff);
    aggr_kernel<<<BB * (CC / 2), THREADS, 0, stream>>>(inp, ord, toff, out);
  } else {
    seg_avg_kernel<<<BB * (CC / 4), THREADS, 0, stream>>>(inp, seg, out);
  }
}

// Round 9
// 368.282 us; speedup vs baseline: 1.5730x; 1.5730x over previous
//
#include <hip/hip_runtime.h>

// Segment-average pooling, sort + single-phase ping-pong LDS scatter/reduce.
//   input  [B=8, C=128, N=65536] fp32, labels [B, N] int32 in [0, 1024)
//   out    [B, S=1024, C=128] fp32 segment means
//
// R9: R8 proved gathers are address-divergence-bound (382 us, 50 GB/s).
// R7 counters proved the two-barrier phased scatter kernel is NOT BW-bound
// (L3-hot reps same speed): the load-drain each tile has only ~1k cyc of
// reduce work to hide under, by construction. Restructure the K-loop:
// double-buffered LDS, ONE lds_barrier per tile, scatter(k)+prefetch(k+1)+
// reduce(k-1) merged in a single phase -> loads always in flight, HBM duty
// -> ~90%. TILE=2048, float2 (2-ch blocks), 40KB LDS, 2 blocks/CU.

#define BB 8
#define CC 128
#define NPIX 65536      // 256*256
#define SS 1024
#define TILE 2048
#define NTILES (NPIX / TILE)   // 32
#define THREADS 1024

#define POS_ELEMS (BB * NPIX)           // u16 sorted position within tile
#define OFF_ELEMS (BB * NTILES * SS)    // u16 exclusive offsets per tile

// size-preserving XOR swizzle: e=8q+r -> 8q + (r ^ (q&7)); bijective,
// spreads reduce-run banks, costs 1 VALU op, no LDS padding.
__device__ __forceinline__ int swz(int e) { return e ^ ((e >> 3) & 7); }

// LDS-only barrier: orders LDS across waves WITHOUT draining vmcnt, so
// prefetched global loads stay in flight across it.
__device__ __forceinline__ void lds_barrier() {
  asm volatile("s_waitcnt lgkmcnt(0)\n\ts_barrier" ::: "memory");
}

// ---------------- Kernel A: per-tile counting sort metadata ----------------
__global__ __launch_bounds__(THREADS, 1) void sort_kernel(
    const int* __restrict__ seg, unsigned short* __restrict__ pos,
    unsigned short* __restrict__ tileoff) {
  __shared__ unsigned int hist[SS];
  __shared__ unsigned int wsum[16];
  const int b   = blockIdx.x / NTILES;
  const int t   = blockIdx.x % NTILES;
  const int tid = threadIdx.x;

  hist[tid] = 0u;   // THREADS == SS
  __syncthreads();

  const int base = b * NPIX + t * TILE;
  const int2 lab = reinterpret_cast<const int2*>(seg + base)[tid];
  const unsigned int r0 = atomicAdd(&hist[lab.x], 1u);
  const unsigned int r1 = atomicAdd(&hist[lab.y], 1u);
  __syncthreads();

  const unsigned int cnt = hist[tid];
  // inclusive wave-scan (64 lanes, shuffle, no barriers)
  unsigned int v = cnt;
  #pragma unroll
  for (int off = 1; off < 64; off <<= 1) {
    const unsigned int u = __shfl_up(v, off);
    if ((tid & 63) >= off) v += u;
  }
  const int w = tid >> 6;
  if ((tid & 63) == 63) wsum[w] = v;
  __syncthreads();
  if (tid < 16) {   // scan the 16 wave totals
    unsigned int x = wsum[tid];
    #pragma unroll
    for (int off = 1; off < 16; off <<= 1) {
      const unsigned int u = __shfl_up(x, off);
      if (tid >= off) x += u;
    }
    wsum[tid] = x;
  }
  __syncthreads();
  const unsigned int woff = (w == 0) ? 0u : wsum[w - 1];
  const unsigned int excl = woff + v - cnt;   // exclusive offset of segment tid
  tileoff[(b * NTILES + t) * SS + tid] = (unsigned short)excl;
  hist[tid] = excl;
  __syncthreads();

  ushort2 p2;
  p2.x = (unsigned short)(hist[lab.x] + r0);
  p2.y = (unsigned short)(hist[lab.y] + r1);
  reinterpret_cast<ushort2*>(pos + base)[tid] = p2;
}

// ---------------- Kernel B: single-phase ping-pong scatter/reduce ----------
// 512 blocks = (image b, channel pair c0); 2 blocks/CU; thread == segment.
__global__ __launch_bounds__(THREADS, 8) void aggr_kernel(
    const float* __restrict__ inp, const unsigned short* __restrict__ pos,
    const unsigned short* __restrict__ tileoff, float* __restrict__ out) {
  __shared__ float2 buf[2][TILE];               // 2 x 16 KiB ping-pong
  __shared__ unsigned short offl[2][SS + 1];    // ping-pong offsets

  const int b   = blockIdx.x >> 6;          // / (CC/2)
  const int c0  = (blockIdx.x & 63) << 1;   // channel pair base
  const int s   = threadIdx.x;              // segment id
  const int tphase = (blockIdx.x & 1) ? (NTILES / 2) : 0;  // desync pair

  const float* __restrict__ pl0 = inp + ((size_t)b * CC + c0) * NPIX;
  const float* __restrict__ pl1 = pl0 + NPIX;
  const unsigned short* __restrict__ pbase = pos + b * NPIX;
  const unsigned short* __restrict__ tob = tileoff + b * NTILES * SS;

  float a0 = 0.f, a1 = 0.f;
  int cnt = 0;

  // preload first tile into registers
  int tcur = tphase;
  float2 cv0 = reinterpret_cast<const float2*>(pl0 + tcur * TILE)[s];
  float2 cv1 = reinterpret_cast<const float2*>(pl1 + tcur * TILE)[s];
  ushort2 cp = reinterpret_cast<const ushort2*>(pbase + tcur * TILE)[s];
  unsigned short coff = tob[tcur * SS + s];

  for (int k = 0; k < NTILES; ++k) {
    const int cur = k & 1;
    const int prv = cur ^ 1;

    // ---- scatter tile k into buf[cur] (vmcnt wait lands here) ----
    if (s == 0) offl[cur][SS] = (unsigned short)TILE;
    offl[cur][s] = coff;
    buf[cur][swz(cp.x)] = make_float2(cv0.x, cv1.x);
    buf[cur][swz(cp.y)] = make_float2(cv0.y, cv1.y);

    // ---- prefetch tile k+1 (loads stay in flight across the barrier) ----
    const int kn = (k + 1 < NTILES) ? k + 1 : k;
    const int tn = (kn + tphase) & (NTILES - 1);
    const float2 nv0 = reinterpret_cast<const float2*>(pl0 + tn * TILE)[s];
    const float2 nv1 = reinterpret_cast<const float2*>(pl1 + tn * TILE)[s];
    const ushort2 np = reinterpret_cast<const ushort2*>(pbase + tn * TILE)[s];
    const unsigned short noff = tob[tn * SS + s];

    // ---- reduce tile k-1 from buf[prv] (visible since last barrier) ----
    if (k > 0) {
      const int beg = offl[prv][s];
      const int end = offl[prv][s + 1];
      cnt += end - beg;
      int j = beg;
      for (; j + 2 <= end; j += 2) {
        const float2 u = buf[prv][swz(j)];
        const float2 v = buf[prv][swz(j + 1)];
        a0 += u.x + v.x; a1 += u.y + v.y;
      }
      if (j < end) {
        const float2 u = buf[prv][swz(j)];
        a0 += u.x; a1 += u.y;
      }
    }

    lds_barrier();   // one barrier per tile: publishes scatter(k),
                     // retires reduce(k-1) before buf[prv] is rewritten
    cv0 = nv0; cv1 = nv1; cp = np; coff = noff;
  }

  // epilogue: reduce the final scattered tile
  {
    const int prv = (NTILES - 1) & 1;
    const int beg = offl[prv][s];
    const int end = offl[prv][s + 1];
    cnt += end - beg;
    int j = beg;
    for (; j + 2 <= end; j += 2) {
      const float2 u = buf[prv][swz(j)];
      const float2 v = buf[prv][swz(j + 1)];
      a0 += u.x + v.x; a1 += u.y + v.y;
    }
    if (j < end) {
      const float2 u = buf[prv][swz(j)];
      a0 += u.x; a1 += u.y;
    }
  }

  const float inv = 1.0f / (float)max(cnt, 1);
  reinterpret_cast<float2*>(out + ((size_t)(b * SS + s)) * CC + c0)[0] =
      make_float2(a0 * inv, a1 * inv);
}

// ---------------- Fallback (R2): LDS-atomic version, needs no ws -----------
__global__ __launch_bounds__(THREADS, 1) void seg_avg_kernel(
    const float* __restrict__ inp, const int* __restrict__ seg,
    float* __restrict__ out) {
  __shared__ float acc[SS * 5];
  const int b   = blockIdx.x >> 5;
  const int c0  = (blockIdx.x & 31) << 2;
  const int tid = threadIdx.x;
  for (int i = tid; i < SS * 5; i += THREADS) acc[i] = 0.0f;
  __syncthreads();
  const float4* __restrict__ p0 =
      reinterpret_cast<const float4*>(inp + ((size_t)b * CC + c0) * NPIX);
  const int4* __restrict__ lab = reinterpret_cast<const int4*>(seg + (size_t)b * NPIX);
  const int Q = NPIX / 4;
  int* iacc = reinterpret_cast<int*>(acc);
  for (int i = 0; i < NPIX / (4 * THREADS); ++i) {
    const int p = i * THREADS + tid;
    const int4 s4 = lab[p];
    const float4 v0 = p0[p], v1 = p0[p + Q], v2 = p0[p + 2 * Q], v3 = p0[p + 3 * Q];
    const int a0 = s4.x * 5, a1 = s4.y * 5, a2 = s4.z * 5, a3 = s4.w * 5;
    unsafeAtomicAdd(&acc[a0 + 0], v0.x); unsafeAtomicAdd(&acc[a0 + 1], v1.x);
    unsafeAtomicAdd(&acc[a0 + 2], v2.x); unsafeAtomicAdd(&acc[a0 + 3], v3.x);
    atomicAdd(&iacc[a0 + 4], 1);
    unsafeAtomicAdd(&acc[a1 + 0], v0.y); unsafeAtomicAdd(&acc[a1 + 1], v1.y);
    unsafeAtomicAdd(&acc[a1 + 2], v2.y); unsafeAtomicAdd(&acc[a1 + 3], v3.y);
    atomicAdd(&iacc[a1 + 4], 1);
    unsafeAtomicAdd(&acc[a2 + 0], v0.z); unsafeAtomicAdd(&acc[a2 + 1], v1.z);
    unsafeAtomicAdd(&acc[a2 + 2], v2.z); unsafeAtomicAdd(&acc[a2 + 3], v3.z);
    atomicAdd(&iacc[a2 + 4], 1);
    unsafeAtomicAdd(&acc[a3 + 0], v0.w); unsafeAtomicAdd(&acc[a3 + 1], v1.w);
    unsafeAtomicAdd(&acc[a3 + 2], v2.w); unsafeAtomicAdd(&acc[a3 + 3], v3.w);
    atomicAdd(&iacc[a3 + 4], 1);
  }
  __syncthreads();
  for (int i = tid; i < SS * 4; i += THREADS) {
    const int s = i >> 2, c = i & 3;
    const float cntf = (float)iacc[s * 5 + 4];
    out[((size_t)(b * SS + s)) * CC + c0 + c] = acc[s * 5 + c] / fmaxf(cntf, 1.0f);
  }
}

extern "C" void kernel_launch(void* const* d_in, const int* in_sizes, int n_in,
                              void* d_out, int out_size, void* d_ws, size_t ws_size,
                              hipStream_t stream) {
  const float* inp = (const float*)d_in[0];
  const int*   seg = (const int*)d_in[1];
  float*       out = (float*)d_out;

  const size_t need = (size_t)POS_ELEMS * 2 + (size_t)OFF_ELEMS * 2;  // 1.5 MiB
  if (ws_size >= need) {
    unsigned short* pos  = (unsigned short*)d_ws;
    unsigned short* toff = pos + POS_ELEMS;
    sort_kernel<<<BB * NTILES, THREADS, 0, stream>>>(seg, pos, toff);
    aggr_kernel<<<BB * (CC / 2), THREADS, 0, stream>>>(inp, pos, toff, out);
  } else {
    seg_avg_kernel<<<BB * (CC / 4), THREADS, 0, stream>>>(inp, seg, out);
  }
}